// Round 19
// baseline (167.146 us; speedup 1.0000x reference)
//
#include <hip/hip_runtime.h>
#include <math.h>

#define NGRID 9801
#define NB 11            // blocks per dim (both scales)
#define NBLK (NB*NB)     // 121
#define BATCH 16
#define NFEAT 36

typedef float v2f __attribute__((ext_vector_type(2)));   // -> v_pk_*_f32

// ---------------- tables ----------------
__global__ void init_tables(float* __restrict__ rgam, float* __restrict__ convt,
                            float* __restrict__ meanf, float* __restrict__ w1d) {
    int i = blockIdx.x * blockDim.x + threadIdx.x;
    if (i < NGRID) {
        double a = (double)(float)(0.2 + 0.001 * (double)i);  // match float32 grid
        double g1 = lgamma(1.0 / a);
        double g2 = lgamma(2.0 / a);
        double g3 = lgamma(3.0 / a);
        rgam[i]  = (float)exp(2.0 * g2 - g1 - g3);
        convt[i] = (float)sqrt(exp(g1 - g3));
        meanf[i] = (float)exp(g2 - g1);
    }
    if (i == 0) {
        double g[7], s = 0.0;
        for (int k = 0; k < 7; ++k) { double d = (double)(k - 3); g[k] = exp(-d * d * 18.0 / 49.0); s += g[k]; }
        for (int k = 0; k < 7; ++k) w1d[k] = (float)(g[k] / s);
    }
}

__device__ __forceinline__ float bperm(int addr, float v) {
    return __int_as_float(__builtin_amdgcn_ds_bpermute(addr, __float_as_int(v)));
}
// DPP wave shifts (VALU pipe, not DS). Validated rounds 11-18 (absmax 0).
__device__ __forceinline__ float dpp_getL(float v) {   // lane i <- lane i-1
    return __int_as_float(__builtin_amdgcn_update_dpp(
        0, __float_as_int(v), 0x138 /*WAVE_SHR1*/, 0xF, 0xF, true));
}
__device__ __forceinline__ float dpp_getR(float v) {   // lane i <- lane i+1
    return __int_as_float(__builtin_amdgcn_update_dpp(
        0, __float_as_int(v), 0x130 /*WAVE_SHL1*/, 0xF, 0xF, true));
}

// ---------------- fused MSCN + in-register per-block stats (pipelined) --------
// EXACT round-12 hot kernels (best measured: fused96 = 86 us @ VGPR 56;
// fused48 = 24-row strips / 128 thr, 1.5x halo).
//   K=96: 2 slabs(48 cols) x 2 strips(48 rows) = 4 waves (256 thr)
//   K=48: 1 slab x 2 strips(24 rows) = 2 waves (128 thr)
template <int K, bool WDS, int NSTRIPT>
__global__ __launch_bounds__((K / 48) * NSTRIPT * 64) void fused_mscn_stats(
        const float* __restrict__ img, float* __restrict__ dsout,
        const float* __restrict__ w1d, float* __restrict__ stats) {
    constexpr int NSLAB = K / 48;
    constexpr int NSTRIP = NSTRIPT;
    constexpr int WAVES = NSLAB * NSTRIP;
    constexpr int SROWS = K / NSTRIP;
    constexpr int W = K * NB;
    constexpr int H = W;

    __shared__ float lastrow[NSTRIP][K];            // each strip's last norm row
    __shared__ float edgeL[NSTRIP][NSLAB][SROWS];   // per-row slab-edge norm (K=96)
    __shared__ float edgeR[NSTRIP][NSLAB][SROWS];
    __shared__ float redf[WAVES][15];
    __shared__ float redc[WAVES][10];

    const int tid = threadIdx.x;
    const int lane = tid & 63;
    const int wv = tid >> 6;
    const int slab = wv % NSLAB;
    const int strip = wv / NSLAB;
    const int bIdx = blockIdx.x;
    const int b = blockIdx.y;
    const int bh = bIdx / NB, bw = bIdx % NB;
    const int x0 = bw * K + slab * 48;
    const int gx = x0 - 3 + lane;
    const int gxc = min(max(gx, 0), W - 1);
    const int r0 = bh * K + strip * SROWS;
    const bool act = (lane >= 3) && (lane <= 50);
    int am1 = 0, ap1 = 0;
    if constexpr (NSLAB == 1) {
        am1 = ((lane == 3) ? 50 : (lane - 1)) << 2;   // circular product wrap
        ap1 = ((lane == 50) ? 3 : (lane + 1)) << 2;
    }

    const char* baseB = (const char*)(img + (size_t)b * H * W);
    const float w0=w1d[0], w1=w1d[1], w2=w1d[2], w3=w1d[3], w4=w1d[4], w5=w1d[5], w6=w1d[6];

    // incremental addressing: per-lane byte offset + uniform clamped delta
    int addrB = (min(max(r0 - 3, 0), H - 1) * W + gxc) * 4;
    int rowNext = r0 - 2;                  // uniform: row index of NEXT load
    auto ld = [&]() -> float {
        float v = *(const float*)(baseB + addrB);
        addrB += (rowNext >= 1 && rowNext < H) ? (W * 4) : 0;  // uniform SALU
        ++rowNext;
        return v;
    };

    float pa0, pa1, pa2, pa4, pa5, pa6, vHp;
    auto issue_raw = [&](float v) {
        pa2 = dpp_getL(v);        // lane i-1
        pa1 = dpp_getL(pa2);      // lane i-2
        pa0 = dpp_getL(pa1);      // lane i-3
        pa4 = dpp_getR(v);        // lane i+1
        pa5 = dpp_getR(pa4);      // lane i+2
        pa6 = dpp_getR(pa5);      // lane i+3
        vHp = v;
    };
    auto sq2 = [](float v) -> v2f { v2f t; t.x = v; t.y = v * v; return t; };
    // packed combine: [mu_row, m2_row] via 7x v_pk_fma
    auto combine_raw = [&]() -> v2f {
        v2f r = sq2(pa0) * w0;
        r += sq2(pa1) * w1;
        r += sq2(pa2) * w2;
        r += sq2(vHp) * w3;
        r += sq2(pa4) * w4;
        r += sq2(pa5) * w5;
        r += sq2(pa6) * w6;
        return r;
    };

    v2f accp[5];       // [sr2, ssq] per signal
    float sab[5];
    #pragma unroll
    for (int s = 0; s < 5; ++s) { accp[s] = (v2f)0.f; sab[s] = 0.f; }
    int cl[5] = {0,0,0,0,0}, cr[5] = {0,0,0,0,0};

    auto upd = [&](int s, float v) {
        float vp = fmaxf(v, 0.f);
        v2f t; t.x = vp; t.y = v;
        accp[s] += t * t;                      // pk: sr2 += vp^2, ssq += v^2
        sab[s] += fabsf(v);
        cl[s] += __popcll(__ballot(v < 0.f));
        cr[s] += __popcll(__ballot(v > 0.f));
    };

    // prologue: fill 7-row hconv ring (rows r0-3 .. r0+3) + pend row r0+4
    v2f mq0,mq1,mq2,mq3,mq4,mq5,mq6;
    float rA, rB, rC, rD;
    float vN = ld();
    { float v=vN; vN=ld(); issue_raw(v); mq0=combine_raw(); }
    { float v=vN; vN=ld(); issue_raw(v); mq1=combine_raw(); }
    { float v=vN; vN=ld(); issue_raw(v); mq2=combine_raw(); }
    { float v=vN; vN=ld(); issue_raw(v); mq3=combine_raw(); rA=v; }
    { float v=vN; vN=ld(); issue_raw(v); mq4=combine_raw(); rB=v; }
    { float v=vN; vN=ld(); issue_raw(v); mq5=combine_raw(); rC=v; }
    { float v=vN; vN=ld(); issue_raw(v); mq6=combine_raw(); rD=v; }
    { float v=vN; vN=ld(); issue_raw(v); }   // pends = row r0+4; vN = r0+5
    float vN2 = ld();                        // r0+6
    float vN3 = ld();                        // r0+7
    float vN4 = ld();                        // r0+8  (4-deep prefetch)

    float normP = 0.f, normP2 = 0.f;
    float pendSL = 0.f, pendPL = 0.f, pendPR = 0.f;
    float firstN = 0.f, dsSave = 0.f;
    const bool dsw = WDS && (lane & 1) && (lane >= 3) && (lane <= 49);

    #pragma unroll 4
    for (int yy = 0; yy < SROWS; ++yy) {
        const int y = r0 + yy;
        // 1) stats for row y-1 (pend shifts issued last iter)
        if (yy > 0) {
            upd(0, normP);
            upd(1, normP * pendSL);
            upd(2, normP * normP2);
            upd(3, normP * pendPL);
            upd(4, normP * pendPR);
        }
        // 2) vertical combine for row y (packed [mu, s2])
        v2f ms = mq0 * w0;
        ms += mq1 * w1;
        ms += mq2 * w2;
        ms += mq3 * w3;
        ms += mq4 * w4;
        ms += mq5 * w5;
        ms += mq6 * w6;
        float mu = ms.x, s2 = ms.y;
        float sig = __builtin_amdgcn_sqrtf(fabsf(s2 - mu * mu));
        float nrm = (rA - mu) * __builtin_amdgcn_rcpf(sig + 1.0f);
        float cur = act ? nrm : 0.f;

        // 3) captures
        if (yy == 0) firstN = cur;
        if constexpr (NSLAB == 2) {
            if (lane == 3)  edgeL[strip][slab][yy] = cur;
            if (lane == 50) edgeR[strip][slab][yy] = cur;
        }
        if (yy == SROWS - 1 && act) lastrow[strip][slab * 48 + lane - 3] = cur;

        // 4) fused 2x2-mean downsample of raw input (DPP, not DS)
        if constexpr (WDS) {
            float hs = rA + dpp_getR(rA);
            if ((y & 1) == 0) dsSave = hs;
            else if (dsw)
                dsout[((size_t)b * (H / 2) + (y >> 1)) * (W / 2) + (gx >> 1)] = 0.25f * (dsSave + hs);
        }

        // 5) product shifts for next iteration's stats
        if constexpr (NSLAB == 2) {
            pendSL = dpp_getL(cur);      // cur[i-1]; lane3 gets 0 -> fixup
            pendPL = dpp_getL(normP);    // prev[i-1]
            pendPR = dpp_getR(normP);    // prev[i+1]
        } else {
            pendSL = bperm(am1, cur);
            pendPL = bperm(am1, normP);
            pendPR = bperm(ap1, normP);
        }
        normP2 = normP; normP = cur;

        // 6) hconv combine for row y+4 (pends issued last iter) + ring shift
        v2f mh = combine_raw();
        mq0=mq1; mq1=mq2; mq2=mq3; mq3=mq4; mq4=mq5; mq5=mq6; mq6=mh;

        // 7) raw ring shift, issue next raw shifts, rotate 4-deep prefetch
        rA=rB; rB=rC; rC=rD; rD=vHp;
        float vv = vN; vN=vN2; vN2=vN3; vN3=vN4; vN4=ld();
        issue_raw(vv);
    }
    // epilogue: stats for the strip's last row
    upd(0, normP);
    upd(1, normP * pendSL);
    upd(2, normP * normP2);
    upd(3, normP * pendPL);
    upd(4, normP * pendPR);

    __syncthreads();

    // ---- row-seam fixup: products of row r0 with block-circular previous row ----
    {
        const int ps = (strip + NSTRIP - 1) % NSTRIP;
        int j  = slab * 48 + (lane - 3);
        int js = act ? j : 0;
        int jm1 = (js + K - 1) % K;
        int jp1 = (js + 1) % K;
        float pv  = act ? lastrow[ps][js]  : 0.f;
        float pvL = act ? lastrow[ps][jm1] : 0.f;
        float pvR = act ? lastrow[ps][jp1] : 0.f;
        upd(2, firstN * pv);
        upd(3, firstN * pvL);
        upd(4, firstN * pvR);
    }

    // ---- column-seam fixup (K=96 only): slab-edge wrap products ----
    if constexpr (NSLAB == 2) {
        if (lane < SROWS) {
            int r = lane;
            if (slab == 0) {
                float c0  = edgeL[strip][0][r];   // n[r][0]
                float e95 = edgeR[strip][1][r];   // n[r][95]
                upd(1, c0 * e95);
                if (r > 0) {
                    upd(3, c0 * edgeR[strip][1][r - 1]);
                    upd(4, edgeR[strip][0][r] * edgeL[strip][1][r - 1]);  // col47 * n[r-1][48]
                }
            } else {
                float c48 = edgeL[strip][1][r];   // n[r][48]
                float e47 = edgeR[strip][0][r];   // n[r][47]
                upd(1, c48 * e47);
                if (r > 0) {
                    upd(3, c48 * edgeR[strip][0][r - 1]);
                    upd(4, edgeR[strip][1][r] * edgeL[strip][0][r - 1]); // col95 * n[r-1][0]
                }
            }
        }
    }

    // ---- reduce ----
    #pragma unroll
    for (int off = 32; off >= 1; off >>= 1)
        #pragma unroll
        for (int s = 0; s < 5; ++s) {
            accp[s].x += __shfl_down(accp[s].x, off);
            accp[s].y += __shfl_down(accp[s].y, off);
            sab[s]    += __shfl_down(sab[s],    off);
        }
    if (lane == 0) {
        #pragma unroll
        for (int s = 0; s < 5; ++s) {
            redf[wv][s*3+0] = accp[s].x;
            redf[wv][s*3+1] = accp[s].y;
            redf[wv][s*3+2] = sab[s];
            redc[wv][s*2+0] = (float)cl[s];
            redc[wv][s*2+1] = (float)cr[s];
        }
    }
    __syncthreads();
    if (tid < 15) {
        float s = 0.f;
        #pragma unroll
        for (int w = 0; w < WAVES; ++w) s += redf[w][tid];
        stats[((size_t)b * NBLK + bIdx) * 25 + tid] = s;
    } else if (tid < 25) {
        int t = tid - 15;
        float s = 0.f;
        #pragma unroll
        for (int w = 0; w < WAVES; ++w) s += redc[w][t];
        stats[((size_t)b * NBLK + bIdx) * 25 + tid] = s;
    }
}

// ---------------- AGGD closed-form + binary-search argmin ----------------
__global__ __launch_bounds__(256) void aggd_kernel(
        const float* __restrict__ stats1, const float* __restrict__ stats2,
        const float* __restrict__ rgam, const float* __restrict__ convt,
        const float* __restrict__ meanf, float* __restrict__ feats) {
    __shared__ float rg[NGRID];
    for (int i = threadIdx.x; i < NGRID; i += 256) rg[i] = rgam[i];
    __syncthreads();

    int gid = blockIdx.x * 256 + threadIdx.x;
    if (gid >= 2 * BATCH * NBLK * 5) return;
    int s = gid % 5; int t = gid / 5;
    int blk = t % NBLK; t /= NBLK;
    int b = t % BATCH; int scale = t / BATCH;

    const float* st = (scale ? stats2 : stats1) + ((size_t)b * NBLK + blk) * 25;
    float sr2 = st[s*3+0], ssq = st[s*3+1], sab = st[s*3+2];
    float cl = st[15 + 2*s], cr = st[15 + 2*s + 1];
    float sl2 = fmaxf(ssq - sr2, 0.f);
    float n = scale ? (48.f * 48.f) : (96.f * 96.f);

    float lstd = sqrtf(sl2 / (cl + 1e-8f));
    float rstd = sqrtf(sr2 / (cr + 1e-8f));
    float gh = lstd / rstd;
    float mab = sab / n;
    float msq = ssq / n;
    float rhat = mab * mab / msq;
    float g2 = gh * gh;
    float x = rhat * (gh * g2 + 1.f) * (gh + 1.f) / ((g2 + 1.f) * (g2 + 1.f));

    int lo = 0, hi = NGRID;
    while (lo < hi) {
        int mid = (lo + hi) >> 1;
        if (rg[mid] < x) lo = mid + 1; else hi = mid;
    }
    int gi;
    if (lo <= 0) gi = 0;
    else if (lo >= NGRID) gi = NGRID - 1;
    else {
        float dlo = x - rg[lo - 1];
        float dhi = rg[lo] - x;
        gi = (dlo <= dhi) ? lo - 1 : lo;   // tie -> lower index (first-min)
    }

    float alpha = (float)(0.2 + 0.001 * (double)gi);
    float cv = convt[gi];
    float lb = lstd * cv, rb = rstd * cv;
    float* fo = feats + ((size_t)b * NBLK + blk) * NFEAT + (scale ? 18 : 0);
    if (s == 0) {
        fo[0] = alpha;
        fo[1] = 0.5f * (lb + rb);
    } else {
        int o = 2 + (s - 1) * 4;
        fo[o]     = alpha;
        fo[o + 1] = (rb - lb) * meanf[gi];
        fo[o + 2] = lb;
        fo[o + 3] = rb;
    }
}

// ---------------- per-batch covariance (f32) + single-wave register solve ----
// Validated round 18 (absmax 0). cov is SPD (lambda_min >= 0.25) -> f32
// no-pivot elimination; lane r owns row r in registers; zero solve barriers.
__global__ __launch_bounds__(256) void score_kernel(
        const float* __restrict__ feats, const float* __restrict__ mu_pris,
        const float* __restrict__ cov_pris, float* __restrict__ out) {
    __shared__ float F[NBLK][NFEAT];
    __shared__ float Af[NFEAT][NFEAT + 1];
    __shared__ double mu[NFEAT];
    __shared__ float dffF[NFEAT];
    int b = blockIdx.x, tid = threadIdx.x;
    const float* fp = feats + (size_t)b * NBLK * NFEAT;
    for (int i = tid; i < NBLK * NFEAT; i += 256) F[i / NFEAT][i % NFEAT] = fp[i];
    __syncthreads();
    if (tid < NFEAT) {
        double s = 0.0;
        for (int n = 0; n < NBLK; ++n) s += (double)F[n][tid];
        double m = s / (double)NBLK;
        mu[tid] = m;
        dffF[tid] = (float)((double)mu_pris[tid] - m);
    }
    __syncthreads();
    for (int e = tid; e < NFEAT * NFEAT; e += 256) {
        int f = e / NFEAT, g = e % NFEAT;
        float mf = (float)mu[f], mg = (float)mu[g];
        float s = 0.f;
        for (int n = 0; n < NBLK; ++n) s += (F[n][f] - mf) * (F[n][g] - mg);
        Af[f][g] = (s / (float)(NBLK - 1) + cov_pris[f * NFEAT + g]) * 0.5f;
    }
    if (tid < NFEAT) Af[tid][NFEAT] = dffF[tid];
    __syncthreads();

    if (tid < 64) {
        const int r = tid;
        const int rr = (r < NFEAT) ? r : 0;      // lanes 36..63 carry a dummy row
        float a[NFEAT + 1];
        #pragma unroll
        for (int c = 0; c <= NFEAT; ++c) a[c] = Af[rr][c];

        // forward elimination (no pivoting; SPD)
        for (int k = 0; k < NFEAT - 1; ++k) {
            float ark = 0.f;                      // a[k] via static-select chain
            #pragma unroll
            for (int c = 0; c < NFEAT; ++c) if (c == k) ark = a[c];
            float pkk = __shfl(ark, k);           // A[k][k]
            float fac = ark / pkk;                // garbage for r<=k (unused)
            #pragma unroll
            for (int c = 0; c <= NFEAT; ++c) {
                float pkc = __shfl(a[c], k);      // pivot row element
                if (c > k && r > k && r < NFEAT) a[c] -= fac * pkc;
            }
        }
        // back substitution
        float xr = 0.f;
        for (int i = NFEAT - 1; i >= 0; --i) {
            float ai = 0.f;                       // a[i] via static-select chain
            #pragma unroll
            for (int c = 0; c < NFEAT; ++c) if (c == i) ai = a[c];
            float xi = __shfl(a[NFEAT], i) / __shfl(ai, i);
            if (r == i) xr = xi;
            if (r < i) a[NFEAT] -= ai * xi;
        }
        float contrib = (r < NFEAT) ? dffF[r] * xr : 0.f;
        #pragma unroll
        for (int off = 32; off >= 1; off >>= 1) contrib += __shfl_down(contrib, off);
        if (r == 0) out[b] = sqrtf(fmaxf(contrib, 0.f));
    }
}

// ---------------- launch ----------------
extern "C" void kernel_launch(void* const* d_in, const int* in_sizes, int n_in,
                              void* d_out, int out_size, void* d_ws, size_t ws_size,
                              hipStream_t stream) {
    const float* img      = (const float*)d_in[0];
    const float* mu_pris  = (const float*)d_in[1];
    const float* cov_pris = (const float*)d_in[2];
    float* out = (float*)d_out;
    float* ws = (float*)d_ws;

    float* rgam  = ws;                 // 9801 (pad to 9856)
    float* convt = rgam + 9856;
    float* meanf = convt + 9856;
    float* w1d   = meanf + 9856;       // 8
    float* stats1 = w1d + 8;                           // 16*121*25
    float* stats2 = stats1 + BATCH * NBLK * 25;
    float* feats  = stats2 + BATCH * NBLK * 25;        // 16*121*36
    float* dsimg  = feats + BATCH * NBLK * NFEAT;      // 16*528*528

    init_tables<<<(NGRID + 255) / 256, 256, 0, stream>>>(rgam, convt, meanf, w1d);

    fused_mscn_stats<96, true, 2><<<dim3(NBLK, BATCH), 256, 0, stream>>>(
        img, dsimg, w1d, stats1);
    fused_mscn_stats<48, false, 2><<<dim3(NBLK, BATCH), 128, 0, stream>>>(
        dsimg, nullptr, w1d, stats2);

    aggd_kernel<<<(2 * BATCH * NBLK * 5 + 255) / 256, 256, 0, stream>>>(
        stats1, stats2, rgam, convt, meanf, feats);

    score_kernel<<<BATCH, 256, 0, stream>>>(feats, mu_pris, cov_pris, out);
}

// Round 20
// 157.713 us; speedup vs baseline: 1.0598x; 1.0598x over previous
//
#include <hip/hip_runtime.h>
#include <math.h>

#define NGRID 9801
#define NB 11            // blocks per dim (both scales)
#define NBLK (NB*NB)     // 121
#define BATCH 16
#define NFEAT 36

typedef float v2f __attribute__((ext_vector_type(2)));   // -> v_pk_*_f32

// ---------------- tables ----------------
__global__ void init_tables(float* __restrict__ rgam, float* __restrict__ convt,
                            float* __restrict__ meanf, float* __restrict__ w1d) {
    int i = blockIdx.x * blockDim.x + threadIdx.x;
    if (i < NGRID) {
        double a = (double)(float)(0.2 + 0.001 * (double)i);  // match float32 grid
        double g1 = lgamma(1.0 / a);
        double g2 = lgamma(2.0 / a);
        double g3 = lgamma(3.0 / a);
        rgam[i]  = (float)exp(2.0 * g2 - g1 - g3);
        convt[i] = (float)sqrt(exp(g1 - g3));
        meanf[i] = (float)exp(g2 - g1);
    }
    if (i == 0) {
        double g[7], s = 0.0;
        for (int k = 0; k < 7; ++k) { double d = (double)(k - 3); g[k] = exp(-d * d * 18.0 / 49.0); s += g[k]; }
        for (int k = 0; k < 7; ++k) w1d[k] = (float)(g[k] / s);
    }
}

__device__ __forceinline__ float bperm(int addr, float v) {
    return __int_as_float(__builtin_amdgcn_ds_bpermute(addr, __float_as_int(v)));
}
// DPP wave shifts (VALU pipe, not DS). Validated rounds 11-19 (absmax 0).
__device__ __forceinline__ float dpp_getL(float v) {   // lane i <- lane i-1
    return __int_as_float(__builtin_amdgcn_update_dpp(
        0, __float_as_int(v), 0x138 /*WAVE_SHR1*/, 0xF, 0xF, true));
}
__device__ __forceinline__ float dpp_getR(float v) {   // lane i <- lane i+1
    return __int_as_float(__builtin_amdgcn_update_dpp(
        0, __float_as_int(v), 0x130 /*WAVE_SHL1*/, 0xF, 0xF, true));
}

// ---------------- fused MSCN + in-register per-block stats (pipelined) --------
// One WG per (NIQE block, batch). Round-12 structure (best measured, 157.8us):
//   K=96: 2 slabs(48 cols) x 2 strips(48 rows) = 4 waves (256 thr).
//   K=48: 1 slab x 4 strips(12 rows) = 4 waves (256 thr).
template <int K, bool WDS>
__global__ __launch_bounds__(256) void fused_mscn_stats(
        const float* __restrict__ img, float* __restrict__ dsout,
        const float* __restrict__ w1d, float* __restrict__ stats) {
    constexpr int NSLAB = K / 48;
    constexpr int NSTRIP = 4 / NSLAB;
    constexpr int SROWS = K / NSTRIP;
    constexpr int W = K * NB;
    constexpr int H = W;

    __shared__ float lastrow[NSTRIP][K];            // each strip's last norm row
    __shared__ float edgeL[NSTRIP][NSLAB][SROWS];   // per-row slab-edge norm (K=96)
    __shared__ float edgeR[NSTRIP][NSLAB][SROWS];
    __shared__ float redf[4][15];
    __shared__ float redc[4][10];

    const int tid = threadIdx.x;
    const int lane = tid & 63;
    const int wv = tid >> 6;
    const int slab = wv % NSLAB;
    const int strip = wv / NSLAB;
    const int bIdx = blockIdx.x;
    const int b = blockIdx.y;
    const int bh = bIdx / NB, bw = bIdx % NB;
    const int x0 = bw * K + slab * 48;
    const int gx = x0 - 3 + lane;
    const int gxc = min(max(gx, 0), W - 1);
    const int r0 = bh * K + strip * SROWS;
    const bool act = (lane >= 3) && (lane <= 50);
    int am1 = 0, ap1 = 0;
    if constexpr (NSLAB == 1) {
        am1 = ((lane == 3) ? 50 : (lane - 1)) << 2;   // circular product wrap
        ap1 = ((lane == 50) ? 3 : (lane + 1)) << 2;
    }

    const char* baseB = (const char*)(img + (size_t)b * H * W);
    const float w0=w1d[0], w1=w1d[1], w2=w1d[2], w3=w1d[3], w4=w1d[4], w5=w1d[5], w6=w1d[6];

    // incremental addressing: per-lane byte offset + uniform clamped delta
    int addrB = (min(max(r0 - 3, 0), H - 1) * W + gxc) * 4;
    int rowNext = r0 - 2;                  // uniform: row index of NEXT load
    auto ld = [&]() -> float {
        float v = *(const float*)(baseB + addrB);
        addrB += (rowNext >= 1 && rowNext < H) ? (W * 4) : 0;  // uniform SALU
        ++rowNext;
        return v;
    };

    float pa0, pa1, pa2, pa4, pa5, pa6, vHp;
    auto issue_raw = [&](float v) {
        pa2 = dpp_getL(v);        // lane i-1
        pa1 = dpp_getL(pa2);      // lane i-2
        pa0 = dpp_getL(pa1);      // lane i-3
        pa4 = dpp_getR(v);        // lane i+1
        pa5 = dpp_getR(pa4);      // lane i+2
        pa6 = dpp_getR(pa5);      // lane i+3
        vHp = v;
    };
    auto sq2 = [](float v) -> v2f { v2f t; t.x = v; t.y = v * v; return t; };
    // packed combine: [mu_row, m2_row] via 7x v_pk_fma
    auto combine_raw = [&]() -> v2f {
        v2f r = sq2(pa0) * w0;
        r += sq2(pa1) * w1;
        r += sq2(pa2) * w2;
        r += sq2(vHp) * w3;
        r += sq2(pa4) * w4;
        r += sq2(pa5) * w5;
        r += sq2(pa6) * w6;
        return r;
    };

    v2f accp[5];       // [sr2, ssq] per signal
    float sab[5];
    #pragma unroll
    for (int s = 0; s < 5; ++s) { accp[s] = (v2f)0.f; sab[s] = 0.f; }
    int cl[5] = {0,0,0,0,0}, cr[5] = {0,0,0,0,0};

    auto upd = [&](int s, float v) {
        float vp = fmaxf(v, 0.f);
        v2f t; t.x = vp; t.y = v;
        accp[s] += t * t;                      // pk: sr2 += vp^2, ssq += v^2
        sab[s] += fabsf(v);
        cl[s] += __popcll(__ballot(v < 0.f));
        cr[s] += __popcll(__ballot(v > 0.f));
    };

    // prologue: fill 7-row hconv ring (rows r0-3 .. r0+3) + pend row r0+4
    v2f mq0,mq1,mq2,mq3,mq4,mq5,mq6;
    float rA, rB, rC, rD;
    float vN = ld();
    { float v=vN; vN=ld(); issue_raw(v); mq0=combine_raw(); }
    { float v=vN; vN=ld(); issue_raw(v); mq1=combine_raw(); }
    { float v=vN; vN=ld(); issue_raw(v); mq2=combine_raw(); }
    { float v=vN; vN=ld(); issue_raw(v); mq3=combine_raw(); rA=v; }
    { float v=vN; vN=ld(); issue_raw(v); mq4=combine_raw(); rB=v; }
    { float v=vN; vN=ld(); issue_raw(v); mq5=combine_raw(); rC=v; }
    { float v=vN; vN=ld(); issue_raw(v); mq6=combine_raw(); rD=v; }
    { float v=vN; vN=ld(); issue_raw(v); }   // pends = row r0+4; vN = r0+5
    float vN2 = ld();                        // r0+6
    float vN3 = ld();                        // r0+7
    float vN4 = ld();                        // r0+8  (4-deep prefetch)

    float normP = 0.f, normP2 = 0.f;
    float pendSL = 0.f, pendPL = 0.f, pendPR = 0.f;
    float firstN = 0.f, dsSave = 0.f;
    const bool dsw = WDS && (lane & 1) && (lane >= 3) && (lane <= 49);

    #pragma unroll 4
    for (int yy = 0; yy < SROWS; ++yy) {
        const int y = r0 + yy;
        // 1) stats for row y-1 (pend shifts issued last iter)
        if (yy > 0) {
            upd(0, normP);
            upd(1, normP * pendSL);
            upd(2, normP * normP2);
            upd(3, normP * pendPL);
            upd(4, normP * pendPR);
        }
        // 2) vertical combine for row y (packed [mu, s2])
        v2f ms = mq0 * w0;
        ms += mq1 * w1;
        ms += mq2 * w2;
        ms += mq3 * w3;
        ms += mq4 * w4;
        ms += mq5 * w5;
        ms += mq6 * w6;
        float mu = ms.x, s2 = ms.y;
        float sig = __builtin_amdgcn_sqrtf(fabsf(s2 - mu * mu));
        float nrm = (rA - mu) * __builtin_amdgcn_rcpf(sig + 1.0f);
        float cur = act ? nrm : 0.f;

        // 3) captures
        if (yy == 0) firstN = cur;
        if constexpr (NSLAB == 2) {
            if (lane == 3)  edgeL[strip][slab][yy] = cur;
            if (lane == 50) edgeR[strip][slab][yy] = cur;
        }
        if (yy == SROWS - 1 && act) lastrow[strip][slab * 48 + lane - 3] = cur;

        // 4) fused 2x2-mean downsample of raw input (DPP, not DS)
        if constexpr (WDS) {
            float hs = rA + dpp_getR(rA);
            if ((y & 1) == 0) dsSave = hs;
            else if (dsw)
                dsout[((size_t)b * (H / 2) + (y >> 1)) * (W / 2) + (gx >> 1)] = 0.25f * (dsSave + hs);
        }

        // 5) product shifts for next iteration's stats
        if constexpr (NSLAB == 2) {
            pendSL = dpp_getL(cur);      // cur[i-1]; lane3 gets 0 -> fixup
            pendPL = dpp_getL(normP);    // prev[i-1]
            pendPR = dpp_getR(normP);    // prev[i+1]
        } else {
            pendSL = bperm(am1, cur);
            pendPL = bperm(am1, normP);
            pendPR = bperm(ap1, normP);
        }
        normP2 = normP; normP = cur;

        // 6) hconv combine for row y+4 (pends issued last iter) + ring shift
        v2f mh = combine_raw();
        mq0=mq1; mq1=mq2; mq2=mq3; mq3=mq4; mq4=mq5; mq5=mq6; mq6=mh;

        // 7) raw ring shift, issue next raw shifts, rotate 4-deep prefetch
        rA=rB; rB=rC; rC=rD; rD=vHp;
        float vv = vN; vN=vN2; vN2=vN3; vN3=vN4; vN4=ld();
        issue_raw(vv);
    }
    // epilogue: stats for the strip's last row
    upd(0, normP);
    upd(1, normP * pendSL);
    upd(2, normP * normP2);
    upd(3, normP * pendPL);
    upd(4, normP * pendPR);

    __syncthreads();

    // ---- row-seam fixup: products of row r0 with block-circular previous row ----
    {
        const int ps = (strip + NSTRIP - 1) % NSTRIP;
        int j  = slab * 48 + (lane - 3);
        int js = act ? j : 0;
        int jm1 = (js + K - 1) % K;
        int jp1 = (js + 1) % K;
        float pv  = act ? lastrow[ps][js]  : 0.f;
        float pvL = act ? lastrow[ps][jm1] : 0.f;
        float pvR = act ? lastrow[ps][jp1] : 0.f;
        upd(2, firstN * pv);
        upd(3, firstN * pvL);
        upd(4, firstN * pvR);
    }

    // ---- column-seam fixup (K=96 only): slab-edge wrap products ----
    if constexpr (NSLAB == 2) {
        if (lane < SROWS) {
            int r = lane;
            if (slab == 0) {
                float c0  = edgeL[strip][0][r];   // n[r][0]
                float e95 = edgeR[strip][1][r];   // n[r][95]
                upd(1, c0 * e95);
                if (r > 0) {
                    upd(3, c0 * edgeR[strip][1][r - 1]);
                    upd(4, edgeR[strip][0][r] * edgeL[strip][1][r - 1]);  // col47 * n[r-1][48]
                }
            } else {
                float c48 = edgeL[strip][1][r];   // n[r][48]
                float e47 = edgeR[strip][0][r];   // n[r][47]
                upd(1, c48 * e47);
                if (r > 0) {
                    upd(3, c48 * edgeR[strip][0][r - 1]);
                    upd(4, edgeR[strip][1][r] * edgeL[strip][0][r - 1]); // col95 * n[r-1][0]
                }
            }
        }
    }

    // ---- reduce: 15 floats via shuffles; counts via LDS ----
    #pragma unroll
    for (int off = 32; off >= 1; off >>= 1)
        #pragma unroll
        for (int s = 0; s < 5; ++s) {
            accp[s].x += __shfl_down(accp[s].x, off);
            accp[s].y += __shfl_down(accp[s].y, off);
            sab[s]    += __shfl_down(sab[s],    off);
        }
    if (lane == 0) {
        #pragma unroll
        for (int s = 0; s < 5; ++s) {
            redf[wv][s*3+0] = accp[s].x;
            redf[wv][s*3+1] = accp[s].y;
            redf[wv][s*3+2] = sab[s];
            redc[wv][s*2+0] = (float)cl[s];
            redc[wv][s*2+1] = (float)cr[s];
        }
    }
    __syncthreads();
    if (tid < 15) {
        stats[((size_t)b * NBLK + bIdx) * 25 + tid] =
            redf[0][tid] + redf[1][tid] + redf[2][tid] + redf[3][tid];
    } else if (tid < 25) {
        int t = tid - 15;
        stats[((size_t)b * NBLK + bIdx) * 25 + tid] =
            redc[0][t] + redc[1][t] + redc[2][t] + redc[3][t];
    }
}

// ---------------- AGGD closed-form + binary-search argmin ----------------
__global__ __launch_bounds__(256) void aggd_kernel(
        const float* __restrict__ stats1, const float* __restrict__ stats2,
        const float* __restrict__ rgam, const float* __restrict__ convt,
        const float* __restrict__ meanf, float* __restrict__ feats) {
    __shared__ float rg[NGRID];
    for (int i = threadIdx.x; i < NGRID; i += 256) rg[i] = rgam[i];
    __syncthreads();

    int gid = blockIdx.x * 256 + threadIdx.x;
    if (gid >= 2 * BATCH * NBLK * 5) return;
    int s = gid % 5; int t = gid / 5;
    int blk = t % NBLK; t /= NBLK;
    int b = t % BATCH; int scale = t / BATCH;

    const float* st = (scale ? stats2 : stats1) + ((size_t)b * NBLK + blk) * 25;
    float sr2 = st[s*3+0], ssq = st[s*3+1], sab = st[s*3+2];
    float cl = st[15 + 2*s], cr = st[15 + 2*s + 1];
    float sl2 = fmaxf(ssq - sr2, 0.f);
    float n = scale ? (48.f * 48.f) : (96.f * 96.f);

    float lstd = sqrtf(sl2 / (cl + 1e-8f));
    float rstd = sqrtf(sr2 / (cr + 1e-8f));
    float gh = lstd / rstd;
    float mab = sab / n;
    float msq = ssq / n;
    float rhat = mab * mab / msq;
    float g2 = gh * gh;
    float x = rhat * (gh * g2 + 1.f) * (gh + 1.f) / ((g2 + 1.f) * (g2 + 1.f));

    int lo = 0, hi = NGRID;
    while (lo < hi) {
        int mid = (lo + hi) >> 1;
        if (rg[mid] < x) lo = mid + 1; else hi = mid;
    }
    int gi;
    if (lo <= 0) gi = 0;
    else if (lo >= NGRID) gi = NGRID - 1;
    else {
        float dlo = x - rg[lo - 1];
        float dhi = rg[lo] - x;
        gi = (dlo <= dhi) ? lo - 1 : lo;   // tie -> lower index (first-min)
    }

    float alpha = (float)(0.2 + 0.001 * (double)gi);
    float cv = convt[gi];
    float lb = lstd * cv, rb = rstd * cv;
    float* fo = feats + ((size_t)b * NBLK + blk) * NFEAT + (scale ? 18 : 0);
    if (s == 0) {
        fo[0] = alpha;
        fo[1] = 0.5f * (lb + rb);
    } else {
        int o = 2 + (s - 1) * 4;
        fo[o]     = alpha;
        fo[o + 1] = (rb - lb) * meanf[gi];
        fo[o + 2] = lb;
        fo[o + 3] = rb;
    }
}

// ---------------- per-batch covariance + solve + score ----------------
__global__ __launch_bounds__(256) void score_kernel(
        const float* __restrict__ feats, const float* __restrict__ mu_pris,
        const float* __restrict__ cov_pris, float* __restrict__ out) {
    __shared__ float F[NBLK][NFEAT];
    __shared__ double mu[NFEAT];
    __shared__ double A[NFEAT][NFEAT + 1];
    __shared__ double dff[NFEAT];
    __shared__ double xs[NFEAT];
    int b = blockIdx.x, tid = threadIdx.x;
    const float* fp = feats + (size_t)b * NBLK * NFEAT;
    for (int i = tid; i < NBLK * NFEAT; i += 256) F[i / NFEAT][i % NFEAT] = fp[i];
    __syncthreads();
    if (tid < NFEAT) {
        double s = 0.0;
        for (int n = 0; n < NBLK; ++n) s += (double)F[n][tid];
        mu[tid] = s / (double)NBLK;
        dff[tid] = (double)mu_pris[tid] - mu[tid];
    }
    __syncthreads();
    for (int e = tid; e < NFEAT * NFEAT; e += 256) {
        int f = e / NFEAT, g = e % NFEAT;
        double mf = mu[f], mg = mu[g];
        double s = 0.0;
        for (int n = 0; n < NBLK; ++n) s += ((double)F[n][f] - mf) * ((double)F[n][g] - mg);
        A[f][g] = (s / (double)(NBLK - 1) + (double)cov_pris[f * NFEAT + g]) * 0.5;
    }
    if (tid < NFEAT) A[tid][NFEAT] = dff[tid];
    for (int k = 0; k < NFEAT - 1; ++k) {
        __syncthreads();
        double rk = 1.0 / A[k][k];
        for (int e = tid; e < NFEAT * (NFEAT + 1); e += 256) {
            int r = e / (NFEAT + 1), c = e % (NFEAT + 1);
            if (r > k && c > k) A[r][c] -= (A[r][k] * rk) * A[k][c];
        }
    }
    __syncthreads();
    for (int i = NFEAT - 1; i >= 0; --i) {
        if (tid == i) xs[i] = A[i][NFEAT] / A[i][i];
        __syncthreads();
        if (tid < i) A[tid][NFEAT] -= A[tid][i] * xs[i];
    }
    __syncthreads();
    if (tid == 0) {
        double quad = 0.0;
        for (int i = 0; i < NFEAT; ++i) quad += dff[i] * xs[i];
        out[b] = (float)sqrt(fmax(quad, 0.0));
    }
}

// ---------------- launch ----------------
extern "C" void kernel_launch(void* const* d_in, const int* in_sizes, int n_in,
                              void* d_out, int out_size, void* d_ws, size_t ws_size,
                              hipStream_t stream) {
    const float* img      = (const float*)d_in[0];
    const float* mu_pris  = (const float*)d_in[1];
    const float* cov_pris = (const float*)d_in[2];
    float* out = (float*)d_out;
    float* ws = (float*)d_ws;

    float* rgam  = ws;                 // 9801 (pad to 9856)
    float* convt = rgam + 9856;
    float* meanf = convt + 9856;
    float* w1d   = meanf + 9856;       // 8
    float* stats1 = w1d + 8;                           // 16*121*25
    float* stats2 = stats1 + BATCH * NBLK * 25;
    float* feats  = stats2 + BATCH * NBLK * 25;        // 16*121*36
    float* dsimg  = feats + BATCH * NBLK * NFEAT;      // 16*528*528

    init_tables<<<(NGRID + 255) / 256, 256, 0, stream>>>(rgam, convt, meanf, w1d);

    fused_mscn_stats<96, true><<<dim3(NBLK, BATCH), 256, 0, stream>>>(
        img, dsimg, w1d, stats1);
    fused_mscn_stats<48, false><<<dim3(NBLK, BATCH), 256, 0, stream>>>(
        dsimg, nullptr, w1d, stats2);

    aggd_kernel<<<(2 * BATCH * NBLK * 5 + 255) / 256, 256, 0, stream>>>(
        stats1, stats2, rgam, convt, meanf, feats);

    score_kernel<<<BATCH, 256, 0, stream>>>(feats, mu_pris, cov_pris, out);
}